// Round 3
// baseline (49.131 us; speedup 1.0000x reference)
//
#include <hip/hip_runtime.h>
#include <hip/hip_bf16.h>

#define TV    512
#define TL    64
#define D_    512
#define BKT   64
#define VROWS 128
#define NCHUNK (TV/VROWS)   // 4
#define NKT   (D_/BKT)      // 8

typedef __attribute__((ext_vector_type(8))) short bf16x8;
typedef __attribute__((ext_vector_type(4))) float f32x4;

__global__ __launch_bounds__(256) void chamfer_main(
    const float* __restrict__ vf, const float* __restrict__ lf,
    const float* __restrict__ mv, const float* __restrict__ ml,
    float* __restrict__ pcol, float* __restrict__ psum)
{
  const int chunk = blockIdx.x;
  const int b     = blockIdx.y;
  const int t     = threadIdx.x;
  const int w     = t >> 6;
  const int lane  = t & 63;
  const int g     = lane >> 4;
  const int c15   = lane & 15;

  // L tile for the whole batch: 64 rows x 512 k, bf16, swizzled. Read-only
  // after the single prologue barrier -> barrier-free main loop.
  __shared__ __align__(16) short ll[TL * D_];      // 64 KiB
  __shared__ float normp[4][TL];
  __shared__ float normv_s[VROWS];
  __shared__ float norml_s[TL];
  __shared__ float mvs[VROWS];
  __shared__ float mls[TL];
  __shared__ float wavecol[4][TL];
  __shared__ float wavesum[4];

  const int v0 = chunk * VROWS;
  const float* vbase = vf + ((size_t)b * TV + v0) * D_;
  const float* lbase = lf + (size_t)b * TL * D_;
  // per-lane V pointer: row = v0 + w*32 + m*16 + c15, k-offset g*8
  const float* vlane = vbase + (size_t)(w * 32 + c15) * D_ + g * 8;

  f32x4 acc[2][4];
  #pragma unroll
  for (int m = 0; m < 2; m++)
    #pragma unroll
    for (int n = 0; n < 4; n++)
      acc[m][n] = (f32x4){0.f, 0.f, 0.f, 0.f};

  float nvp[2] = {0.f, 0.f};

  float4 rvA[2][2][2];
  float4 rvB[2][2][2];

#define VLOAD(R, KT) do {                                                        \
    _Pragma("unroll")                                                            \
    for (int m_ = 0; m_ < 2; m_++)                                               \
      _Pragma("unroll")                                                          \
      for (int ks_ = 0; ks_ < 2; ks_++) {                                        \
        const float4* s_ = (const float4*)(vlane + (size_t)m_ * 16 * D_ +        \
                                           (KT) * BKT + ks_ * 32);               \
        R[m_][ks_][0] = s_[0]; R[m_][ks_][1] = s_[1];                            \
      }                                                                          \
  } while (0)

#define COMPUTE(R, KT) do {                                                      \
    _Pragma("unroll")                                                            \
    for (int ks_ = 0; ks_ < 2; ks_++) {                                          \
      bf16x8 afr_[2], bfr_[4];                                                   \
      _Pragma("unroll")                                                          \
      for (int n_ = 0; n_ < 4; n_++) {                                           \
        int row_ = n_ * 16 + c15;                                                \
        int off_ = (row_ * 1024 + (KT) * 128 + ks_ * 64 + g * 16)                \
                   ^ ((row_ & 7) << 4);                                          \
        bfr_[n_] = *(const bf16x8*)((const char*)ll + off_);                     \
      }                                                                          \
      _Pragma("unroll")                                                          \
      for (int m_ = 0; m_ < 2; m_++) {                                           \
        float4 a_ = R[m_][ks_][0], b_ = R[m_][ks_][1];                           \
        nvp[m_] += a_.x*a_.x + a_.y*a_.y + a_.z*a_.z + a_.w*a_.w                 \
                 + b_.x*b_.x + b_.y*b_.y + b_.z*b_.z + b_.w*b_.w;                \
        union { bf16x8 v8; __hip_bfloat162 h[4]; } u_;                           \
        u_.h[0] = __float22bfloat162_rn(make_float2(a_.x, a_.y));                \
        u_.h[1] = __float22bfloat162_rn(make_float2(a_.z, a_.w));                \
        u_.h[2] = __float22bfloat162_rn(make_float2(b_.x, b_.y));                \
        u_.h[3] = __float22bfloat162_rn(make_float2(b_.z, b_.w));                \
        afr_[m_] = u_.v8;                                                        \
      }                                                                          \
      _Pragma("unroll")                                                          \
      for (int m_ = 0; m_ < 2; m_++)                                             \
        _Pragma("unroll")                                                        \
        for (int n_ = 0; n_ < 4; n_++)                                           \
          acc[m_][n_] = __builtin_amdgcn_mfma_f32_16x16x32_bf16(                 \
              afr_[m_], bfr_[n_], acc[m_][n_], 0, 0, 0);                         \
    }                                                                            \
  } while (0)

  // V tiles 0,1 in flight while L stages
  VLOAD(rvA, 0);
  VLOAD(rvB, 1);

  // ---- prologue: stage all of L (f32 -> bf16, swizzled), norml partials ----
  {
    const int lrow = lane;        // wave w handles k-quarter w
    const float* lsrc = lbase + (size_t)lrow * D_ + w * 128;
    float nlp = 0.f;
    #pragma unroll
    for (int i = 0; i < 16; i++) {
      const float4* s = (const float4*)(lsrc + i * 8);
      float4 a = s[0], bq = s[1];
      nlp += a.x*a.x + a.y*a.y + a.z*a.z + a.w*a.w
           + bq.x*bq.x + bq.y*bq.y + bq.z*bq.z + bq.w*bq.w;
      union { bf16x8 v8; __hip_bfloat162 h[4]; } u;
      u.h[0] = __float22bfloat162_rn(make_float2(a.x, a.y));
      u.h[1] = __float22bfloat162_rn(make_float2(a.z, a.w));
      u.h[2] = __float22bfloat162_rn(make_float2(bq.x, bq.y));
      u.h[3] = __float22bfloat162_rn(make_float2(bq.z, bq.w));
      int off = (lrow * 1024 + w * 256 + i * 16) ^ ((lrow & 7) << 4);
      *(bf16x8*)((char*)ll + off) = u.v8;
    }
    normp[w][lrow] = nlp;
  }
  if (t < VROWS)           mvs[t]         = mv[(size_t)b * TV + v0 + t];
  else if (t < VROWS + TL) mls[t - VROWS] = ml[(size_t)b * TL + (t - VROWS)];
  __syncthreads();
  if (t < TL)
    norml_s[t] = normp[0][t] + normp[1][t] + normp[2][t] + normp[3][t];
  __syncthreads();

  // ---- barrier-free main loop, depth-2 pipeline ----
  COMPUTE(rvA, 0); VLOAD(rvA, 2);
  COMPUTE(rvB, 1); VLOAD(rvB, 3);
  COMPUTE(rvA, 2); VLOAD(rvA, 4);
  COMPUTE(rvB, 3); VLOAD(rvB, 5);
  COMPUTE(rvA, 4); VLOAD(rvA, 6);
  COMPUTE(rvB, 5); VLOAD(rvB, 7);
  COMPUTE(rvA, 6);
  COMPUTE(rvB, 7);
#undef VLOAD
#undef COMPUTE

  // ---- V row-norms: reduce over the 4 g-groups (same c15) ----
  #pragma unroll
  for (int m = 0; m < 2; m++) {
    float s = nvp[m];
    s += __shfl_xor(s, 16);
    s += __shfl_xor(s, 32);
    if (g == 0) normv_s[w * 32 + m * 16 + c15] = s;
  }
  __syncthreads();

  // ---- epilogue: pd + masking, row/col mins ----
  const float BIG = 3.0e38f;
  float pdv[2][4][4];
  #pragma unroll
  for (int m = 0; m < 2; m++)
    #pragma unroll
    for (int n = 0; n < 4; n++)
      #pragma unroll
      for (int j = 0; j < 4; j++) {
        int row = w * 32 + m * 16 + g * 4 + j;
        int col = n * 16 + c15;
        float pd = normv_s[row] + norml_s[col] - 2.0f * acc[m][n][j];
        bool valid = (mvs[row] != 0.f) && (mls[col] != 0.f);
        pdv[m][n][j] = valid ? pd : BIG;
      }

  float svl = 0.f;
  #pragma unroll
  for (int m = 0; m < 2; m++)
    #pragma unroll
    for (int j = 0; j < 4; j++) {
      float rm = fminf(fminf(pdv[m][0][j], pdv[m][1][j]),
                       fminf(pdv[m][2][j], pdv[m][3][j]));
      rm = fminf(rm, __shfl_xor(rm, 1));
      rm = fminf(rm, __shfl_xor(rm, 2));
      rm = fminf(rm, __shfl_xor(rm, 4));
      rm = fminf(rm, __shfl_xor(rm, 8));
      int row = w * 32 + m * 16 + g * 4 + j;
      if (c15 == 0 && mvs[row] != 0.f) svl += rm;
    }
  svl += __shfl_xor(svl, 16);
  svl += __shfl_xor(svl, 32);
  if (lane == 0) wavesum[w] = svl;

  #pragma unroll
  for (int n = 0; n < 4; n++) {
    float cm = pdv[0][n][0];
    #pragma unroll
    for (int m = 0; m < 2; m++)
      #pragma unroll
      for (int j = 0; j < 4; j++)
        cm = fminf(cm, pdv[m][n][j]);
    cm = fminf(cm, __shfl_xor(cm, 16));
    cm = fminf(cm, __shfl_xor(cm, 32));
    if (g == 0) wavecol[w][n * 16 + c15] = cm;
  }
  __syncthreads();

  if (t < TL) {
    float cm = fminf(fminf(wavecol[0][t], wavecol[1][t]),
                     fminf(wavecol[2][t], wavecol[3][t]));
    pcol[((size_t)b * NCHUNK + chunk) * TL + t] = cm;
  }
  if (t == 0)
    psum[(size_t)b * NCHUNK + chunk] = wavesum[0] + wavesum[1] + wavesum[2] + wavesum[3];
}

__global__ __launch_bounds__(64) void chamfer_fin(
    const float* __restrict__ pcol, const float* __restrict__ psum,
    const float* __restrict__ mv, const float* __restrict__ ml,
    float* __restrict__ out)
{
  int b = blockIdx.x;
  int l = threadIdx.x;
  float cm = pcol[((size_t)b * 4 + 0) * 64 + l];
  cm = fminf(cm, pcol[((size_t)b * 4 + 1) * 64 + l]);
  cm = fminf(cm, pcol[((size_t)b * 4 + 2) * 64 + l]);
  cm = fminf(cm, pcol[((size_t)b * 4 + 3) * 64 + l]);
  float mlv = ml[(size_t)b * 64 + l];
  float sl = (mlv != 0.f) ? cm : 0.f;
  float nl = mlv;
  float nv = 0.f;
  #pragma unroll
  for (int i = 0; i < 8; i++) nv += mv[(size_t)b * 512 + l * 8 + i];
  float sv = (l < 4) ? psum[(size_t)b * 4 + l] : 0.f;
  #pragma unroll
  for (int s = 1; s < 64; s <<= 1) {
    sl += __shfl_xor(sl, s);
    nl += __shfl_xor(nl, s);
    nv += __shfl_xor(nv, s);
    sv += __shfl_xor(sv, s);
  }
  if (l == 0) out[b] = sl / nl + sv / nv;
}

extern "C" void kernel_launch(void* const* d_in, const int* in_sizes, int n_in,
                              void* d_out, int out_size, void* d_ws, size_t ws_size,
                              hipStream_t stream) {
  const float* vf = (const float*)d_in[0];
  const float* lf = (const float*)d_in[1];
  const float* mv = (const float*)d_in[2];
  const float* ml = (const float*)d_in[3];
  float* out  = (float*)d_out;
  float* pcol = (float*)d_ws;                  // [128][4][64]
  float* psum = pcol + 128 * 4 * 64;           // [128][4]
  dim3 grid(NCHUNK, 128);
  chamfer_main<<<grid, 256, 0, stream>>>(vf, lf, mv, ml, pcol, psum);
  chamfer_fin<<<128, 64, 0, stream>>>(pcol, psum, mv, ml, out);
}

// Round 4
// 33.098 us; speedup vs baseline: 1.4844x; 1.4844x over previous
//
#include <hip/hip_runtime.h>
#include <hip/hip_bf16.h>

#define TV    512
#define TL    64
#define D_    512
#define BKT   64
#define VROWS 64
#define NCHUNK (TV/VROWS)   // 8
#define NKT   (D_/BKT)      // 8

typedef __attribute__((ext_vector_type(8))) short bf16x8;
typedef __attribute__((ext_vector_type(4))) float f32x4;

__global__ __launch_bounds__(256, 4) void chamfer_main(
    const float* __restrict__ vf, const float* __restrict__ lf,
    const float* __restrict__ mv, const float* __restrict__ ml,
    float* __restrict__ pcol, float* __restrict__ psum)
{
  // XCD-aware decode: all 8 chunks of a batch land on the same XCD
  // (XCD = linear_id % 8 on MI355X), so the shared L-slice stays L2-hot.
  const int lin   = blockIdx.x;          // 0..1023
  const int xcd   = lin & 7;
  const int kk    = lin >> 3;            // 0..127
  const int chunk = kk & 7;
  const int b     = ((kk >> 3) << 3) | xcd;   // bijective over 0..127

  const int t     = threadIdx.x;
  const int w     = t >> 6;
  const int lane  = t & 63;
  const int g     = lane >> 4;
  const int c15   = lane & 15;

  __shared__ __align__(16) short lv[VROWS * BKT];  // 8 KiB, swizzled bf16 V
  __shared__ __align__(16) short ll[TL * BKT];     // 8 KiB, swizzled bf16 L
  __shared__ float normv_s[VROWS];
  __shared__ float norml_s[TL];
  __shared__ float mvs[VROWS];
  __shared__ float mls[TL];
  __shared__ float wavecol[4][TL];
  __shared__ float wavesum[4];

  const int v0 = chunk * VROWS;
  const float* vbase = vf + ((size_t)b * TV + v0) * D_;
  const float* lbase = lf + (size_t)b * TL * D_;

  if (t < VROWS)                mvs[t]        = mv[(size_t)b * TV + v0 + t];
  else if (t < VROWS + TL)      mls[t - VROWS] = ml[(size_t)b * TL + (t - VROWS)];

  f32x4 acc[4];
  #pragma unroll
  for (int n = 0; n < 4; n++) acc[n] = (f32x4){0.f, 0.f, 0.f, 0.f};

  float nvacc[2] = {0.f, 0.f};
  float nlacc[2] = {0.f, 0.f};

  for (int kt = 0; kt < NKT; ++kt) {
    // ---- stage V and L tiles (64 rows x 64 k each, bf16, swizzled) ----
    #pragma unroll
    for (int p = 0; p < 2; p++) {
      int idx = p * 256 + t;          // 0..511
      int row = idx >> 3, kc = idx & 7;
      int off = (row * 128 + kc * 16) ^ ((row & 7) << 4);

      const float4* sv_ = (const float4*)(vbase + (size_t)row * D_ + kt * BKT + kc * 8);
      float4 a = sv_[0], bq = sv_[1];
      nvacc[p] += a.x*a.x + a.y*a.y + a.z*a.z + a.w*a.w
                + bq.x*bq.x + bq.y*bq.y + bq.z*bq.z + bq.w*bq.w;
      union { bf16x8 v8; __hip_bfloat162 h[4]; } u;
      u.h[0] = __float22bfloat162_rn(make_float2(a.x, a.y));
      u.h[1] = __float22bfloat162_rn(make_float2(a.z, a.w));
      u.h[2] = __float22bfloat162_rn(make_float2(bq.x, bq.y));
      u.h[3] = __float22bfloat162_rn(make_float2(bq.z, bq.w));
      *(bf16x8*)((char*)lv + off) = u.v8;

      const float4* sl_ = (const float4*)(lbase + (size_t)row * D_ + kt * BKT + kc * 8);
      float4 c = sl_[0], dq = sl_[1];
      nlacc[p] += c.x*c.x + c.y*c.y + c.z*c.z + c.w*c.w
                + dq.x*dq.x + dq.y*dq.y + dq.z*dq.z + dq.w*dq.w;
      union { bf16x8 v8; __hip_bfloat162 h[4]; } u2;
      u2.h[0] = __float22bfloat162_rn(make_float2(c.x, c.y));
      u2.h[1] = __float22bfloat162_rn(make_float2(c.z, c.w));
      u2.h[2] = __float22bfloat162_rn(make_float2(dq.x, dq.y));
      u2.h[3] = __float22bfloat162_rn(make_float2(dq.z, dq.w));
      *(bf16x8*)((char*)ll + off) = u2.v8;
    }
    __syncthreads();
    // ---- MFMA: 2 k-steps of 32; wave owns 16 v-rows ----
    #pragma unroll
    for (int ks = 0; ks < 2; ks++) {
      bf16x8 afr, bfr[4];
      {
        int row = w * 16 + c15;
        int off = (row * 128 + ks * 64 + g * 16) ^ ((row & 7) << 4);
        afr = *(const bf16x8*)((const char*)lv + off);
      }
      #pragma unroll
      for (int n = 0; n < 4; n++) {
        int row = n * 16 + c15;
        int off = (row * 128 + ks * 64 + g * 16) ^ ((row & 7) << 4);
        bfr[n] = *(const bf16x8*)((const char*)ll + off);
      }
      #pragma unroll
      for (int n = 0; n < 4; n++)
        acc[n] = __builtin_amdgcn_mfma_f32_16x16x32_bf16(afr, bfr[n], acc[n], 0, 0, 0);
    }
    __syncthreads();
  }

  // ---- row-norm reductions (8 consecutive lanes share a row) ----
  #pragma unroll
  for (int p = 0; p < 2; p++) {
    float s = nvacc[p];
    s += __shfl_xor(s, 1); s += __shfl_xor(s, 2); s += __shfl_xor(s, 4);
    if ((t & 7) == 0) normv_s[p * 32 + (t >> 3)] = s;
  }
  #pragma unroll
  for (int p = 0; p < 2; p++) {
    float s = nlacc[p];
    s += __shfl_xor(s, 1); s += __shfl_xor(s, 2); s += __shfl_xor(s, 4);
    if ((t & 7) == 0) norml_s[p * 32 + (t >> 3)] = s;
  }
  __syncthreads();

  // ---- epilogue: pd + masking, row/col mins ----
  const float BIG = 3.0e38f;
  float pdv[4][4];   // [n][j]
  #pragma unroll
  for (int n = 0; n < 4; n++)
    #pragma unroll
    for (int j = 0; j < 4; j++) {
      int row = w * 16 + g * 4 + j;
      int col = n * 16 + c15;
      float pd = normv_s[row] + norml_s[col] - 2.0f * acc[n][j];
      bool valid = (mvs[row] != 0.f) && (mls[col] != 0.f);
      pdv[n][j] = valid ? pd : BIG;
    }

  // row mins (over all 64 cols) -> masked sum over this wave's 16 rows
  float svl = 0.f;
  #pragma unroll
  for (int j = 0; j < 4; j++) {
    float rm = fminf(fminf(pdv[0][j], pdv[1][j]),
                     fminf(pdv[2][j], pdv[3][j]));
    rm = fminf(rm, __shfl_xor(rm, 1));
    rm = fminf(rm, __shfl_xor(rm, 2));
    rm = fminf(rm, __shfl_xor(rm, 4));
    rm = fminf(rm, __shfl_xor(rm, 8));
    int row = w * 16 + g * 4 + j;
    if (c15 == 0 && mvs[row] != 0.f) svl += rm;
  }
  svl += __shfl_xor(svl, 16);
  svl += __shfl_xor(svl, 32);
  if (lane == 0) wavesum[w] = svl;

  // col mins over this wave's 16 rows
  #pragma unroll
  for (int n = 0; n < 4; n++) {
    float cm = fminf(fminf(pdv[n][0], pdv[n][1]),
                     fminf(pdv[n][2], pdv[n][3]));
    cm = fminf(cm, __shfl_xor(cm, 16));
    cm = fminf(cm, __shfl_xor(cm, 32));
    if (g == 0) wavecol[w][n * 16 + c15] = cm;
  }
  __syncthreads();

  if (t < TL) {
    float cm = fminf(fminf(wavecol[0][t], wavecol[1][t]),
                     fminf(wavecol[2][t], wavecol[3][t]));
    pcol[((size_t)b * NCHUNK + chunk) * TL + t] = cm;
  }
  if (t == 0)
    psum[(size_t)b * NCHUNK + chunk] = wavesum[0] + wavesum[1] + wavesum[2] + wavesum[3];
}

__global__ __launch_bounds__(64) void chamfer_fin(
    const float* __restrict__ pcol, const float* __restrict__ psum,
    const float* __restrict__ mv, const float* __restrict__ ml,
    float* __restrict__ out)
{
  int b = blockIdx.x;
  int l = threadIdx.x;
  float cm = pcol[((size_t)b * NCHUNK + 0) * 64 + l];
  #pragma unroll
  for (int i = 1; i < NCHUNK; i++)
    cm = fminf(cm, pcol[((size_t)b * NCHUNK + i) * 64 + l]);
  float mlv = ml[(size_t)b * 64 + l];
  float sl = (mlv != 0.f) ? cm : 0.f;
  float nl = mlv;
  float nv = 0.f;
  #pragma unroll
  for (int i = 0; i < 8; i++) nv += mv[(size_t)b * 512 + l * 8 + i];
  float sv = (l < NCHUNK) ? psum[(size_t)b * NCHUNK + l] : 0.f;
  #pragma unroll
  for (int s = 1; s < 64; s <<= 1) {
    sl += __shfl_xor(sl, s);
    nl += __shfl_xor(nl, s);
    nv += __shfl_xor(nv, s);
    sv += __shfl_xor(sv, s);
  }
  if (l == 0) out[b] = sl / nl + sv / nv;
}

extern "C" void kernel_launch(void* const* d_in, const int* in_sizes, int n_in,
                              void* d_out, int out_size, void* d_ws, size_t ws_size,
                              hipStream_t stream) {
  const float* vf = (const float*)d_in[0];
  const float* lf = (const float*)d_in[1];
  const float* mv = (const float*)d_in[2];
  const float* ml = (const float*)d_in[3];
  float* out  = (float*)d_out;
  float* pcol = (float*)d_ws;                       // [128][8][64]
  float* psum = pcol + 128 * NCHUNK * 64;           // [128][8]
  chamfer_main<<<128 * NCHUNK, 256, 0, stream>>>(vf, lf, mv, ml, pcol, psum);
  chamfer_fin<<<128, 64, 0, stream>>>(pcol, psum, mv, ml, out);
}